// Round 6
// baseline (265.257 us; speedup 1.0000x reference)
//
#include <hip/hip_runtime.h>

#define NC 5
#define DICE_EPS 1e-7f

typedef unsigned long long u64;
typedef unsigned int u32;
typedef float v4f __attribute__((ext_vector_type(4)));
typedef int   v4i __attribute__((ext_vector_type(4)));

// Workspace layout (u32 cnt[256], memset to 0 each launch):
// cnt[c*16]        : den1[c] = count(pred == c)      (own cacheline each)
// cnt[(5+c)*16]    : den2[c] = count(mask == c)
// cnt[(10+c)*16]   : num[c]  = count(pred == c && mask == c)

#define BLOCKS 2048
#define GROUPS 2   // per thread: 2 groups x 8 float4 (+ 8 int4) = 64 elems

__device__ __forceinline__ void accum4(v4f pf, v4i mv,
                                       u64& A1, u64& A2, u64& AN)
{
    // Packed 8-bit-per-class counters: class c in bits [8c, 8c+8).
    // Bits [40,48) are a trash bin for "prediction != label".
    int p0 = (int)pf.x, p1 = (int)pf.y, p2 = (int)pf.z, p3 = (int)pf.w;
    int s0 = p0 << 3, s1 = p1 << 3, s2 = p2 << 3, s3 = p3 << 3;
    A1 += (1ull << s0) + (1ull << s1) + (1ull << s2) + (1ull << s3);
    A2 += (1ull << (mv.x << 3)) + (1ull << (mv.y << 3)) +
          (1ull << (mv.z << 3)) + (1ull << (mv.w << 3));
    AN += (1ull << (p0 == mv.x ? s0 : 40)) +
          (1ull << (p1 == mv.y ? s1 : 40)) +
          (1ull << (p2 == mv.z ? s2 : 40)) +
          (1ull << (p3 == mv.w ? s3 : 40));
}

#define FLUSH()                                                         \
    do {                                                                \
        _Pragma("unroll")                                               \
        for (int c = 0; c < NC; ++c) {                                  \
            den1[c] += (u32)(A1 >> (8 * c)) & 0xFF;                     \
            den2[c] += (u32)(A2 >> (8 * c)) & 0xFF;                     \
            num [c] += (u32)(AN >> (8 * c)) & 0xFF;                     \
        }                                                               \
        A1 = 0; A2 = 0; AN = 0;                                         \
    } while (0)

__global__ __launch_bounds__(256) void dice_hist_kernel(
    const float* __restrict__ pred_f, const int* __restrict__ mask,
    u32* __restrict__ cnt, int n)
{
    u32 den1[NC] = {0, 0, 0, 0, 0};
    u32 den2[NC] = {0, 0, 0, 0, 0};
    u32 num [NC] = {0, 0, 0, 0, 0};

    const int tid = threadIdx.x;
    const int n4  = n >> 2;

    const v4f* __restrict__ p4 = (const v4f*)pred_f;
    const v4i* __restrict__ m4 = (const v4i*)mask;

    u64 A1 = 0, A2 = 0, AN = 0;

    const int totalWaves = (int)(gridDim.x * blockDim.x) >> 6;
    const int gstride    = totalWaves * 512;   // float4 elems per group sweep

    if (n4 == gstride * GROUPS) {
        // Fast path: each wave owns 8KB-contiguous chunks per array per group;
        // the grid sweeps memory in lockstep (DRAM-row friendly).
        // 16 loads (256B) in flight per thread before any consumer.
        // Per-thread elems = GROUPS*8*4 = 64 < 256 -> single flush at end.
        const int W    = ((int)(blockIdx.x * blockDim.x) + tid) >> 6;
        const int lane = tid & 63;
        int base = W * 512 + lane;
        #pragma unroll
        for (int g = 0; g < GROUPS; ++g, base += gstride) {
            v4f a0 = __builtin_nontemporal_load(p4 + base);
            v4f a1 = __builtin_nontemporal_load(p4 + base + 64);
            v4f a2 = __builtin_nontemporal_load(p4 + base + 128);
            v4f a3 = __builtin_nontemporal_load(p4 + base + 192);
            v4f a4 = __builtin_nontemporal_load(p4 + base + 256);
            v4f a5 = __builtin_nontemporal_load(p4 + base + 320);
            v4f a6 = __builtin_nontemporal_load(p4 + base + 384);
            v4f a7 = __builtin_nontemporal_load(p4 + base + 448);
            v4i b0 = __builtin_nontemporal_load(m4 + base);
            v4i b1 = __builtin_nontemporal_load(m4 + base + 64);
            v4i b2 = __builtin_nontemporal_load(m4 + base + 128);
            v4i b3 = __builtin_nontemporal_load(m4 + base + 192);
            v4i b4 = __builtin_nontemporal_load(m4 + base + 256);
            v4i b5 = __builtin_nontemporal_load(m4 + base + 320);
            v4i b6 = __builtin_nontemporal_load(m4 + base + 384);
            v4i b7 = __builtin_nontemporal_load(m4 + base + 448);
            // Forbid the scheduler from sinking any load below this point.
            __builtin_amdgcn_sched_barrier(0);
            accum4(a0, b0, A1, A2, AN);
            accum4(a1, b1, A1, A2, AN);
            accum4(a2, b2, A1, A2, AN);
            accum4(a3, b3, A1, A2, AN);
            accum4(a4, b4, A1, A2, AN);
            accum4(a5, b5, A1, A2, AN);
            accum4(a6, b6, A1, A2, AN);
            accum4(a7, b7, A1, A2, AN);
        }
        FLUSH();
    } else {
        // Generic path: plain grid-stride with periodic flush.
        const int nt = gridDim.x * blockDim.x;
        int i = blockIdx.x * blockDim.x + tid;
        int cin = 0;
        for (; i < n4; i += nt) {
            accum4(p4[i], m4[i], A1, A2, AN);
            cin += 4;
            if (cin >= 224) { FLUSH(); cin = 0; }
        }
        FLUSH();
        for (int j = (n4 << 2) + blockIdx.x * blockDim.x + tid; j < n; j += nt) {
            int p = (int)pred_f[j];
            int m = mask[j];
            #pragma unroll
            for (int c = 0; c < NC; ++c) {
                u32 a = (p == c), b = (m == c);
                den1[c] += a;
                den2[c] += b;
                num [c] += a & b;
            }
        }
    }

    // wave-level butterfly reduce (wave = 64 lanes)
    #pragma unroll
    for (int c = 0; c < NC; ++c) {
        #pragma unroll
        for (int off = 32; off > 0; off >>= 1) {
            den1[c] += __shfl_xor(den1[c], off, 64);
            den2[c] += __shfl_xor(den2[c], off, 64);
            num [c] += __shfl_xor(num [c], off, 64);
        }
    }

    __shared__ u32 s_cnt[3 * NC];
    if (tid < 3 * NC) s_cnt[tid] = 0;
    __syncthreads();

    if ((tid & 63) == 0) {
        #pragma unroll
        for (int c = 0; c < NC; ++c) {
            atomicAdd(&s_cnt[c],          den1[c]);
            atomicAdd(&s_cnt[NC + c],     den2[c]);
            atomicAdd(&s_cnt[2 * NC + c], num [c]);
        }
    }
    __syncthreads();

    if (tid < 3 * NC) {
        atomicAdd(&cnt[tid * 16], s_cnt[tid]);
    }
}

__global__ void dice_final_kernel(const u32* __restrict__ cnt,
                                  float* __restrict__ out)
{
    if (blockIdx.x == 0 && threadIdx.x == 0) {
        float s = 0.0f;
        #pragma unroll
        for (int c = 0; c < NC; ++c) {
            float d1 = (float)cnt[c * 16];
            float d2 = (float)cnt[(NC + c) * 16];
            float nm = (float)cnt[(2 * NC + c) * 16];
            s += 2.0f * ((nm + DICE_EPS) / (d1 + d2 + DICE_EPS));
        }
        out[0] = s / (float)NC;
    }
}

extern "C" void kernel_launch(void* const* d_in, const int* in_sizes, int n_in,
                              void* d_out, int out_size, void* d_ws, size_t ws_size,
                              hipStream_t stream) {
    const float* pred = (const float*)d_in[0];   // "output": float32 labels
    const int*   mask = (const int*)d_in[1];     // "mask": int32 labels
    const int n = in_sizes[0];                   // 128*512*512 = 33,554,432

    u32* cnt = (u32*)d_ws;
    hipMemsetAsync(d_ws, 0, 256 * sizeof(u32), stream);

    dice_hist_kernel<<<BLOCKS, 256, 0, stream>>>(pred, mask, cnt, n);
    dice_final_kernel<<<1, 64, 0, stream>>>(cnt, (float*)d_out);
}

// Round 7
// 256.603 us; speedup vs baseline: 1.0337x; 1.0337x over previous
//
#include <hip/hip_runtime.h>

#define NC 5
#define DICE_EPS 1e-7f

typedef unsigned long long u64;
typedef unsigned int u32;
typedef float v4f __attribute__((ext_vector_type(4)));
typedef int   v4i __attribute__((ext_vector_type(4)));

// Workspace layout (u32 cnt[256], memset to 0 each launch):
// cnt[c*16]        : den1[c] = count(pred == c)      (own cacheline each)
// cnt[(5+c)*16]    : den2[c] = count(mask == c)
// cnt[(10+c)*16]   : num[c]  = count(pred == c && mask == c)

#define BLOCKS 1024
#define GROUPS 8   // per thread per group: 4 float4 + 4 int4 = 16 elems

struct Grp {
    v4f a0, a1, a2, a3;
    v4i b0, b1, b2, b3;
};

__device__ __forceinline__ Grp load_grp(const v4f* __restrict__ p4,
                                        const v4i* __restrict__ m4, int base)
{
    Grp g;
    g.a0 = __builtin_nontemporal_load(p4 + base);
    g.a1 = __builtin_nontemporal_load(p4 + base + 64);
    g.a2 = __builtin_nontemporal_load(p4 + base + 128);
    g.a3 = __builtin_nontemporal_load(p4 + base + 192);
    g.b0 = __builtin_nontemporal_load(m4 + base);
    g.b1 = __builtin_nontemporal_load(m4 + base + 64);
    g.b2 = __builtin_nontemporal_load(m4 + base + 128);
    g.b3 = __builtin_nontemporal_load(m4 + base + 192);
    return g;
}

__device__ __forceinline__ void accum4(v4f pf, v4i mv,
                                       u64& A1, u64& A2, u64& AN)
{
    // Packed 8-bit-per-class counters: class c in bits [8c, 8c+8).
    // Bits [40,48) are a trash bin for "prediction != label".
    int p0 = (int)pf.x, p1 = (int)pf.y, p2 = (int)pf.z, p3 = (int)pf.w;
    int s0 = p0 << 3, s1 = p1 << 3, s2 = p2 << 3, s3 = p3 << 3;
    A1 += (1ull << s0) + (1ull << s1) + (1ull << s2) + (1ull << s3);
    A2 += (1ull << (mv.x << 3)) + (1ull << (mv.y << 3)) +
          (1ull << (mv.z << 3)) + (1ull << (mv.w << 3));
    AN += (1ull << (p0 == mv.x ? s0 : 40)) +
          (1ull << (p1 == mv.y ? s1 : 40)) +
          (1ull << (p2 == mv.z ? s2 : 40)) +
          (1ull << (p3 == mv.w ? s3 : 40));
}

__device__ __forceinline__ void consume_grp(const Grp& g,
                                            u64& A1, u64& A2, u64& AN)
{
    accum4(g.a0, g.b0, A1, A2, AN);
    accum4(g.a1, g.b1, A1, A2, AN);
    accum4(g.a2, g.b2, A1, A2, AN);
    accum4(g.a3, g.b3, A1, A2, AN);
}

#define FLUSH()                                                         \
    do {                                                                \
        _Pragma("unroll")                                               \
        for (int c = 0; c < NC; ++c) {                                  \
            den1[c] += (u32)(A1 >> (8 * c)) & 0xFF;                     \
            den2[c] += (u32)(A2 >> (8 * c)) & 0xFF;                     \
            num [c] += (u32)(AN >> (8 * c)) & 0xFF;                     \
        }                                                               \
        A1 = 0; A2 = 0; AN = 0;                                         \
    } while (0)

__global__ __launch_bounds__(256) void dice_hist_kernel(
    const float* __restrict__ pred_f, const int* __restrict__ mask,
    u32* __restrict__ cnt, int n)
{
    u32 den1[NC] = {0, 0, 0, 0, 0};
    u32 den2[NC] = {0, 0, 0, 0, 0};
    u32 num [NC] = {0, 0, 0, 0, 0};

    const int tid = threadIdx.x;
    const int n4  = n >> 2;

    const v4f* __restrict__ p4 = (const v4f*)pred_f;
    const v4i* __restrict__ m4 = (const v4i*)mask;

    u64 A1 = 0, A2 = 0, AN = 0;

    const int totalWaves = (int)(gridDim.x * blockDim.x) >> 6;
    const int gstride    = totalWaves * 256;   // float4 elems per group sweep

    if (n4 == gstride * GROUPS) {
        // Fast path: each wave owns a contiguous 4KB chunk per array per
        // group; whole grid sweeps memory in lockstep (DRAM-row friendly).
        // 2-stage software pipeline: group g+1's 8 loads are issued BEFORE
        // consuming group g, so consumption waits at vmcnt(8), not vmcnt(0).
        // Per-thread elems = GROUPS*16 = 128 < 256 -> single flush at end.
        const int W    = ((int)(blockIdx.x * blockDim.x) + tid) >> 6;
        const int lane = tid & 63;
        const int base = W * 256 + lane;

        Grp cur = load_grp(p4, m4, base);
        #pragma unroll
        for (int g = 0; g < GROUPS - 1; ++g) {
            Grp nxt = load_grp(p4, m4, base + (g + 1) * gstride);
            // Pin: nxt's loads are issued above; cur's consumers stay below.
            __builtin_amdgcn_sched_barrier(0);
            consume_grp(cur, A1, A2, AN);
            cur = nxt;
        }
        consume_grp(cur, A1, A2, AN);
        FLUSH();
    } else {
        // Generic path: plain grid-stride with periodic flush.
        const int nt = gridDim.x * blockDim.x;
        int i = blockIdx.x * blockDim.x + tid;
        int cin = 0;
        for (; i < n4; i += nt) {
            accum4(p4[i], m4[i], A1, A2, AN);
            cin += 4;
            if (cin >= 224) { FLUSH(); cin = 0; }
        }
        FLUSH();
        for (int j = (n4 << 2) + blockIdx.x * blockDim.x + tid; j < n; j += nt) {
            int p = (int)pred_f[j];
            int m = mask[j];
            #pragma unroll
            for (int c = 0; c < NC; ++c) {
                u32 a = (p == c), b = (m == c);
                den1[c] += a;
                den2[c] += b;
                num [c] += a & b;
            }
        }
    }

    // wave-level butterfly reduce (wave = 64 lanes)
    #pragma unroll
    for (int c = 0; c < NC; ++c) {
        #pragma unroll
        for (int off = 32; off > 0; off >>= 1) {
            den1[c] += __shfl_xor(den1[c], off, 64);
            den2[c] += __shfl_xor(den2[c], off, 64);
            num [c] += __shfl_xor(num [c], off, 64);
        }
    }

    __shared__ u32 s_cnt[3 * NC];
    if (tid < 3 * NC) s_cnt[tid] = 0;
    __syncthreads();

    if ((tid & 63) == 0) {
        #pragma unroll
        for (int c = 0; c < NC; ++c) {
            atomicAdd(&s_cnt[c],          den1[c]);
            atomicAdd(&s_cnt[NC + c],     den2[c]);
            atomicAdd(&s_cnt[2 * NC + c], num [c]);
        }
    }
    __syncthreads();

    if (tid < 3 * NC) {
        atomicAdd(&cnt[tid * 16], s_cnt[tid]);
    }
}

__global__ void dice_final_kernel(const u32* __restrict__ cnt,
                                  float* __restrict__ out)
{
    if (blockIdx.x == 0 && threadIdx.x == 0) {
        float s = 0.0f;
        #pragma unroll
        for (int c = 0; c < NC; ++c) {
            float d1 = (float)cnt[c * 16];
            float d2 = (float)cnt[(NC + c) * 16];
            float nm = (float)cnt[(2 * NC + c) * 16];
            s += 2.0f * ((nm + DICE_EPS) / (d1 + d2 + DICE_EPS));
        }
        out[0] = s / (float)NC;
    }
}

extern "C" void kernel_launch(void* const* d_in, const int* in_sizes, int n_in,
                              void* d_out, int out_size, void* d_ws, size_t ws_size,
                              hipStream_t stream) {
    const float* pred = (const float*)d_in[0];   // "output": float32 labels
    const int*   mask = (const int*)d_in[1];     // "mask": int32 labels
    const int n = in_sizes[0];                   // 128*512*512 = 33,554,432

    u32* cnt = (u32*)d_ws;
    hipMemsetAsync(d_ws, 0, 256 * sizeof(u32), stream);

    dice_hist_kernel<<<BLOCKS, 256, 0, stream>>>(pred, mask, cnt, n);
    dice_final_kernel<<<1, 64, 0, stream>>>(cnt, (float*)d_out);
}